// Round 4
// baseline (399.343 us; speedup 1.0000x reference)
//
#include <hip/hip_runtime.h>

#define NN 100000
#define NE 600000
#define DIN 128
#define DOUT 64
#define SCAN_B 256
#define NBLK ((NN + SCAN_B - 1) / SCAN_B)  // 391

// ---------------- CSR build ----------------
__global__ __launch_bounds__(256) void hist_kernel(const int* __restrict__ ei,
                                                   int* __restrict__ cnt) {
  int e = blockIdx.x * 256 + threadIdx.x;
  if (e < NE) atomicAdd(&cnt[ei[NE + e]], 1);
}

// Phase A: per-block local exclusive scan of 256 counters + block sum
__global__ __launch_bounds__(256) void scan_local_kernel(const int* __restrict__ cnt,
                                                         int* __restrict__ row_ptr,
                                                         int* __restrict__ blk_sum) {
  __shared__ int s[256];
  const int b = blockIdx.x, t = threadIdx.x;
  const int i = b * 256 + t;
  int v = (i < NN) ? cnt[i] : 0;
  s[t] = v;
  __syncthreads();
  for (int off = 1; off < 256; off <<= 1) {
    int u = (t >= off) ? s[t - off] : 0;
    __syncthreads();
    s[t] += u;
    __syncthreads();
  }
  if (i < NN) row_ptr[i] = s[t] - v;  // block-local exclusive
  if (t == 255) blk_sum[b] = s[255];
}

// Phase B: scan the 391 block sums (one block)
__global__ __launch_bounds__(512) void scan_blk_kernel(const int* __restrict__ blk_sum,
                                                       int* __restrict__ blk_off) {
  __shared__ int s[512];
  const int t = threadIdx.x;
  int v = (t < NBLK) ? blk_sum[t] : 0;
  s[t] = v;
  __syncthreads();
  for (int off = 1; off < 512; off <<= 1) {
    int u = (t >= off) ? s[t - off] : 0;
    __syncthreads();
    s[t] += u;
    __syncthreads();
  }
  if (t < NBLK) blk_off[t] = s[t] - v;  // exclusive
}

// Phase C: add block offsets, emit row_ptr and next
__global__ __launch_bounds__(256) void scan_add_kernel(int* __restrict__ row_ptr,
                                                       const int* __restrict__ blk_off,
                                                       int* __restrict__ next) {
  const int b = blockIdx.x, t = threadIdx.x;
  const int i = b * 256 + t;
  if (i < NN) {
    int v = row_ptr[i] + blk_off[b];
    row_ptr[i] = v;
    next[i] = v;
  }
  if (i == 0) row_ptr[NN] = NE;
}

__global__ __launch_bounds__(256) void scatter_kernel(const int* __restrict__ ei,
                                                      const float* __restrict__ ew,
                                                      int* __restrict__ next,
                                                      int* __restrict__ col,
                                                      float* __restrict__ wv) {
  int e = blockIdx.x * 256 + threadIdx.x;
  if (e >= NE) return;
  int src = ei[e];
  int dst = ei[NE + e];
  int pos = atomicAdd(&next[dst], 1);
  col[pos] = src;
  wv[pos] = ew[e];
}

// ---------------- GEMM1: h0 = x @ W1, BK-tiled, both operands in LDS --------
// BM=64, BN=128 (full), BK=32; 256 threads, 8 rows x 4 cols per thread.
#define G1_BM 64
#define G1_BK 32
__global__ __launch_bounds__(256) void gemm1_kernel(const float* __restrict__ x,
                                                    const float* __restrict__ W,
                                                    float* __restrict__ h0) {
  __shared__ float xs[G1_BM][G1_BK + 4];  // stride 36 floats: staging stores conflict-free
  __shared__ float ws[G1_BK][DIN];
  const int t = threadIdx.x;
  const int row0 = blockIdx.x * G1_BM;
  const int j0 = (t & 31) * 4;   // 0..124
  const int r0 = (t >> 5) * 8;   // 0..56
  float4 acc[8];
#pragma unroll
  for (int i = 0; i < 8; ++i) acc[i] = make_float4(0.f, 0.f, 0.f, 0.f);

  for (int k0 = 0; k0 < DIN; k0 += G1_BK) {
    // stage X tile: 64x32 = 512 float4, 2 per thread (coalesced 8 float4/row)
#pragma unroll
    for (int i = 0; i < 2; ++i) {
      int f = t + i * 256;
      int r = f >> 3, c4 = f & 7;
      int gr = row0 + r;
      float4 v = (gr < NN) ? *(const float4*)&x[(size_t)gr * DIN + k0 + c4 * 4]
                           : make_float4(0.f, 0.f, 0.f, 0.f);
      *(float4*)&xs[r][c4 * 4] = v;
    }
    // stage W tile: 32x128 = 1024 float4, 4 per thread
#pragma unroll
    for (int i = 0; i < 4; ++i) {
      int f = t + i * 256;
      int kr = f >> 5, c4 = f & 31;
      *(float4*)&ws[kr][c4 * 4] = *(const float4*)&W[(size_t)(k0 + kr) * DIN + c4 * 4];
    }
    __syncthreads();
#pragma unroll
    for (int k = 0; k < G1_BK; k += 4) {
      float4 b0 = *(const float4*)&ws[k + 0][j0];
      float4 b1 = *(const float4*)&ws[k + 1][j0];
      float4 b2 = *(const float4*)&ws[k + 2][j0];
      float4 b3 = *(const float4*)&ws[k + 3][j0];
#pragma unroll
      for (int i = 0; i < 8; ++i) {
        float4 a = *(const float4*)&xs[r0 + i][k];  // wave-broadcast (same addr per 32 lanes)
        acc[i].x += a.x * b0.x + a.y * b1.x + a.z * b2.x + a.w * b3.x;
        acc[i].y += a.x * b0.y + a.y * b1.y + a.z * b2.y + a.w * b3.y;
        acc[i].z += a.x * b0.z + a.y * b1.z + a.z * b2.z + a.w * b3.z;
        acc[i].w += a.x * b0.w + a.y * b1.w + a.z * b2.w + a.w * b3.w;
      }
    }
    __syncthreads();
  }
#pragma unroll
  for (int i = 0; i < 8; ++i) {
    int gr = row0 + r0 + i;
    if (gr < NN) *(float4*)&h0[(size_t)gr * DIN + j0] = acc[i];
  }
}

// ---------------- GEMM2: h2 = relu(h1 + b1) @ W2, BM=64 ---------------------
// W2 (32 KB) fits L1, so global W2 reads are cheap; keep simple structure.
__global__ __launch_bounds__(256) void gemm2_kernel(const float* __restrict__ h1,
                                                    const float* __restrict__ b1,
                                                    const float* __restrict__ W2,
                                                    float* __restrict__ h2) {
  __shared__ float xs[64][DIN];
  const int t = threadIdx.x;
  const int row0 = blockIdx.x * 64;
#pragma unroll
  for (int i = 0; i < 8; ++i) {
    int f = t + i * 256;
    int r = f >> 5, c4 = f & 31;
    int gr = row0 + r;
    float4 v;
    if (gr < NN) {
      v = *(const float4*)&h1[(size_t)gr * DIN + c4 * 4];
      float4 b = *(const float4*)&b1[c4 * 4];
      v.x = fmaxf(v.x + b.x, 0.f);
      v.y = fmaxf(v.y + b.y, 0.f);
      v.z = fmaxf(v.z + b.z, 0.f);
      v.w = fmaxf(v.w + b.w, 0.f);
    } else {
      v = make_float4(0.f, 0.f, 0.f, 0.f);
    }
    *(float4*)&xs[r][c4 * 4] = v;
  }
  __syncthreads();
  const int j0 = (t & 15) * 4;
  const int r0 = (t >> 4) * 4;
  float4 acc[4];
#pragma unroll
  for (int i = 0; i < 4; ++i) acc[i] = make_float4(0.f, 0.f, 0.f, 0.f);
  for (int k0 = 0; k0 < DIN; k0 += 4) {
    float4 w[4];
#pragma unroll
    for (int kk = 0; kk < 4; ++kk) w[kk] = *(const float4*)&W2[(k0 + kk) * DOUT + j0];
#pragma unroll
    for (int i = 0; i < 4; ++i) {
      float4 xr = *(const float4*)&xs[r0 + i][k0];
      acc[i].x += xr.x * w[0].x + xr.y * w[1].x + xr.z * w[2].x + xr.w * w[3].x;
      acc[i].y += xr.x * w[0].y + xr.y * w[1].y + xr.z * w[2].y + xr.w * w[3].y;
      acc[i].z += xr.x * w[0].z + xr.y * w[1].z + xr.z * w[2].z + xr.w * w[3].z;
      acc[i].w += xr.x * w[0].w + xr.y * w[1].w + xr.z * w[2].w + xr.w * w[3].w;
    }
  }
#pragma unroll
  for (int i = 0; i < 4; ++i) {
    int gr = row0 + r0 + i;
    if (gr < NN) *(float4*)&h2[(size_t)gr * DOUT + j0] = acc[i];
  }
}

// ---------------- gather SpMM: out[r] = sum_{e in row r} w_e * h[col[e]] ----
template <int D, int LPE, bool BIAS>
__global__ __launch_bounds__(256) void spmm_gather_kernel(const int* __restrict__ rp,
                                                          const int* __restrict__ col,
                                                          const float* __restrict__ wv,
                                                          const float* __restrict__ h,
                                                          const float* __restrict__ bias,
                                                          float* __restrict__ out) {
  const int row = blockIdx.x * (256 / LPE) + threadIdx.x / LPE;
  const int lane = threadIdx.x % LPE;
  if (row >= NN) return;
  const int b = rp[row], e = rp[row + 1];
  float4 acc = make_float4(0.f, 0.f, 0.f, 0.f);
  for (int i = b; i < e; ++i) {
    int s = col[i];
    float w = wv[i];
    float4 v = *(const float4*)&h[(size_t)s * D + lane * 4];
    acc.x += w * v.x;
    acc.y += w * v.y;
    acc.z += w * v.z;
    acc.w += w * v.w;
  }
  if (BIAS) {
    float4 bv = ((const float4*)bias)[lane];
    acc.x += bv.x; acc.y += bv.y; acc.z += bv.z; acc.w += bv.w;
  }
  *(float4*)&out[(size_t)row * D + lane * 4] = acc;
}

extern "C" void kernel_launch(void* const* d_in, const int* in_sizes, int n_in,
                              void* d_out, int out_size, void* d_ws, size_t ws_size,
                              hipStream_t stream) {
  const float* x  = (const float*)d_in[0];
  const int*   ei = (const int*)d_in[1];   // [2, E] row-major int32
  const float* ew = (const float*)d_in[2];
  const float* W1 = (const float*)d_in[3];
  const float* b1 = (const float*)d_in[4];
  const float* W2 = (const float*)d_in[5];
  const float* b2 = (const float*)d_in[6];
  float* out = (float*)d_out;

  // workspace layout
  char* p = (char*)d_ws;
  int*   cnt     = (int*)p;                 p += sizeof(int) * NN;
  int*   row_ptr = (int*)p;                 p += sizeof(int) * (NN + 4);
  int*   next    = (int*)p;                 p += sizeof(int) * NN;
  int*   blk_sum = (int*)p;                 p += sizeof(int) * (NBLK + 1);
  int*   blk_off = (int*)p;                 p += sizeof(int) * (NBLK + 1);
  int*   col     = (int*)p;                 p += sizeof(int) * NE;
  float* wv      = (float*)p;               p += sizeof(float) * NE;
  float* h0      = (float*)p;               p += sizeof(float) * (size_t)NN * DIN;
  float* acc1    = (float*)p;               // [NN, DIN]
  float* h2      = h0;                      // reuse h0 region after spmm1

  // CSR build (shared by both layers)
  hipMemsetAsync(cnt, 0, sizeof(int) * NN, stream);
  hist_kernel<<<(NE + 255) / 256, 256, 0, stream>>>(ei, cnt);
  scan_local_kernel<<<NBLK, 256, 0, stream>>>(cnt, row_ptr, blk_sum);
  scan_blk_kernel<<<1, 512, 0, stream>>>(blk_sum, blk_off);
  scan_add_kernel<<<NBLK, 256, 0, stream>>>(row_ptr, blk_off, next);
  scatter_kernel<<<(NE + 255) / 256, 256, 0, stream>>>(ei, ew, next, col, wv);

  // layer 1
  gemm1_kernel<<<(NN + G1_BM - 1) / G1_BM, 256, 0, stream>>>(x, W1, h0);
  spmm_gather_kernel<DIN, 32, false>
      <<<(NN * 32 + 255) / 256, 256, 0, stream>>>(row_ptr, col, wv, h0, nullptr, acc1);

  // layer 2
  gemm2_kernel<<<(NN + 63) / 64, 256, 0, stream>>>(acc1, b1, W2, h2);
  spmm_gather_kernel<DOUT, 16, true>
      <<<(NN * 16 + 255) / 256, 256, 0, stream>>>(row_ptr, col, wv, h2, b2, out);
}

// Round 5
// 363.810 us; speedup vs baseline: 1.0977x; 1.0977x over previous
//
#include <hip/hip_runtime.h>

#define NN 100000
#define NE 600000
#define DIN 128
#define DOUT 64
#define SCAN_B 256
#define NBLK ((NN + SCAN_B - 1) / SCAN_B)  // 391

// ---------------- CSR build ----------------
__global__ __launch_bounds__(256) void hist_kernel(const int* __restrict__ ei,
                                                   int* __restrict__ cnt) {
  int e = blockIdx.x * 256 + threadIdx.x;
  if (e < NE) atomicAdd(&cnt[ei[NE + e]], 1);
}

// Phase A: per-block local exclusive scan of 256 counters + block sum
__global__ __launch_bounds__(256) void scan_local_kernel(const int* __restrict__ cnt,
                                                         int* __restrict__ row_ptr,
                                                         int* __restrict__ blk_sum) {
  __shared__ int s[256];
  const int b = blockIdx.x, t = threadIdx.x;
  const int i = b * 256 + t;
  int v = (i < NN) ? cnt[i] : 0;
  s[t] = v;
  __syncthreads();
  for (int off = 1; off < 256; off <<= 1) {
    int u = (t >= off) ? s[t - off] : 0;
    __syncthreads();
    s[t] += u;
    __syncthreads();
  }
  if (i < NN) row_ptr[i] = s[t] - v;  // block-local exclusive
  if (t == 255) blk_sum[b] = s[255];
}

// Phase B: scan the 391 block sums (one block)
__global__ __launch_bounds__(512) void scan_blk_kernel(const int* __restrict__ blk_sum,
                                                       int* __restrict__ blk_off) {
  __shared__ int s[512];
  const int t = threadIdx.x;
  int v = (t < NBLK) ? blk_sum[t] : 0;
  s[t] = v;
  __syncthreads();
  for (int off = 1; off < 512; off <<= 1) {
    int u = (t >= off) ? s[t - off] : 0;
    __syncthreads();
    s[t] += u;
    __syncthreads();
  }
  if (t < NBLK) blk_off[t] = s[t] - v;  // exclusive
}

// Phase C: add block offsets, emit row_ptr and next
__global__ __launch_bounds__(256) void scan_add_kernel(int* __restrict__ row_ptr,
                                                       const int* __restrict__ blk_off,
                                                       int* __restrict__ next) {
  const int b = blockIdx.x, t = threadIdx.x;
  const int i = b * 256 + t;
  if (i < NN) {
    int v = row_ptr[i] + blk_off[b];
    row_ptr[i] = v;
    next[i] = v;
  }
  if (i == 0) row_ptr[NN] = NE;
}

__global__ __launch_bounds__(256) void scatter_kernel(const int* __restrict__ ei,
                                                      const float* __restrict__ ew,
                                                      int* __restrict__ next,
                                                      int* __restrict__ col,
                                                      float* __restrict__ wv) {
  int e = blockIdx.x * 256 + threadIdx.x;
  if (e >= NE) return;
  int src = ei[e];
  int dst = ei[NE + e];
  int pos = atomicAdd(&next[dst], 1);
  col[pos] = src;
  wv[pos] = ew[e];
}

// ---------------- GEMM1: h0 = x @ W1 ----------------------------------------
// BM=64, 256 threads = 8 rows x 4 cols each. X tile in LDS (32 KB);
// W streamed from global (L1/L2) with 1-step register prefetch.
// VGPR budget kept low on purpose: round-4's dual-LDS-stage version hit
// 160 VGPR -> 9.7% occupancy -> regression.
#define G1_BM 64
__global__ __launch_bounds__(256) void gemm1_kernel(const float* __restrict__ x,
                                                    const float* __restrict__ W,
                                                    float* __restrict__ h0) {
  __shared__ float xs[G1_BM][DIN];  // 32 KB
  const int t = threadIdx.x;
  const int row0 = blockIdx.x * G1_BM;
  // stage 64x128 tile: 2048 float4, 8 per thread (coalesced)
#pragma unroll
  for (int i = 0; i < 8; ++i) {
    int f = t + i * 256;
    int r = f >> 5, c4 = f & 31;
    int gr = row0 + r;
    float4 v = (gr < NN) ? *(const float4*)&x[(size_t)gr * DIN + c4 * 4]
                         : make_float4(0.f, 0.f, 0.f, 0.f);
    *(float4*)&xs[r][c4 * 4] = v;
  }
  __syncthreads();
  const int j0 = (t & 31) * 4;   // 0..124
  const int r0 = (t >> 5) * 8;   // 0..56
  float4 acc[8];
#pragma unroll
  for (int i = 0; i < 8; ++i) acc[i] = make_float4(0.f, 0.f, 0.f, 0.f);

  float4 wc[4], wn[4];
#pragma unroll
  for (int kk = 0; kk < 4; ++kk) wc[kk] = *(const float4*)&W[(size_t)kk * DIN + j0];

  for (int k0 = 0; k0 < DIN; k0 += 4) {
    if (k0 + 4 < DIN) {
#pragma unroll
      for (int kk = 0; kk < 4; ++kk)
        wn[kk] = *(const float4*)&W[(size_t)(k0 + 4 + kk) * DIN + j0];
    }
#pragma unroll
    for (int i = 0; i < 8; ++i) {
      float4 a = *(const float4*)&xs[r0 + i][k0];  // broadcast across 32 lanes
      acc[i].x += a.x * wc[0].x + a.y * wc[1].x + a.z * wc[2].x + a.w * wc[3].x;
      acc[i].y += a.x * wc[0].y + a.y * wc[1].y + a.z * wc[2].y + a.w * wc[3].y;
      acc[i].z += a.x * wc[0].z + a.y * wc[1].z + a.z * wc[2].z + a.w * wc[3].z;
      acc[i].w += a.x * wc[0].w + a.y * wc[1].w + a.z * wc[2].w + a.w * wc[3].w;
    }
#pragma unroll
    for (int kk = 0; kk < 4; ++kk) wc[kk] = wn[kk];
  }
#pragma unroll
  for (int i = 0; i < 8; ++i) {
    int gr = row0 + r0 + i;
    if (gr < NN) *(float4*)&h0[(size_t)gr * DIN + j0] = acc[i];
  }
}

// ---------------- GEMM2: h2 = relu(h1 + b1) @ W2, BM=64 ---------------------
// W2 (32 KB) fits L1; measured fine in round 3 — unchanged.
__global__ __launch_bounds__(256) void gemm2_kernel(const float* __restrict__ h1,
                                                    const float* __restrict__ b1,
                                                    const float* __restrict__ W2,
                                                    float* __restrict__ h2) {
  __shared__ float xs[64][DIN];
  const int t = threadIdx.x;
  const int row0 = blockIdx.x * 64;
#pragma unroll
  for (int i = 0; i < 8; ++i) {
    int f = t + i * 256;
    int r = f >> 5, c4 = f & 31;
    int gr = row0 + r;
    float4 v;
    if (gr < NN) {
      v = *(const float4*)&h1[(size_t)gr * DIN + c4 * 4];
      float4 b = *(const float4*)&b1[c4 * 4];
      v.x = fmaxf(v.x + b.x, 0.f);
      v.y = fmaxf(v.y + b.y, 0.f);
      v.z = fmaxf(v.z + b.z, 0.f);
      v.w = fmaxf(v.w + b.w, 0.f);
    } else {
      v = make_float4(0.f, 0.f, 0.f, 0.f);
    }
    *(float4*)&xs[r][c4 * 4] = v;
  }
  __syncthreads();
  const int j0 = (t & 15) * 4;
  const int r0 = (t >> 4) * 4;
  float4 acc[4];
#pragma unroll
  for (int i = 0; i < 4; ++i) acc[i] = make_float4(0.f, 0.f, 0.f, 0.f);
  for (int k0 = 0; k0 < DIN; k0 += 4) {
    float4 w[4];
#pragma unroll
    for (int kk = 0; kk < 4; ++kk) w[kk] = *(const float4*)&W2[(k0 + kk) * DOUT + j0];
#pragma unroll
    for (int i = 0; i < 4; ++i) {
      float4 xr = *(const float4*)&xs[r0 + i][k0];
      acc[i].x += xr.x * w[0].x + xr.y * w[1].x + xr.z * w[2].x + xr.w * w[3].x;
      acc[i].y += xr.x * w[0].y + xr.y * w[1].y + xr.z * w[2].y + xr.w * w[3].y;
      acc[i].z += xr.x * w[0].z + xr.y * w[1].z + xr.z * w[2].z + xr.w * w[3].z;
      acc[i].w += xr.x * w[0].w + xr.y * w[1].w + xr.z * w[2].w + xr.w * w[3].w;
    }
  }
#pragma unroll
  for (int i = 0; i < 4; ++i) {
    int gr = row0 + r0 + i;
    if (gr < NN) *(float4*)&h2[(size_t)gr * DOUT + j0] = acc[i];
  }
}

// ---------------- gather SpMM: out[r] = sum_{e in row r} w_e * h[col[e]] ----
template <int D, int LPE, bool BIAS>
__global__ __launch_bounds__(256) void spmm_gather_kernel(const int* __restrict__ rp,
                                                          const int* __restrict__ col,
                                                          const float* __restrict__ wv,
                                                          const float* __restrict__ h,
                                                          const float* __restrict__ bias,
                                                          float* __restrict__ out) {
  const int row = blockIdx.x * (256 / LPE) + threadIdx.x / LPE;
  const int lane = threadIdx.x % LPE;
  if (row >= NN) return;
  const int b = rp[row], e = rp[row + 1];
  float4 acc = make_float4(0.f, 0.f, 0.f, 0.f);
  for (int i = b; i < e; ++i) {
    int s = col[i];
    float w = wv[i];
    float4 v = *(const float4*)&h[(size_t)s * D + lane * 4];
    acc.x += w * v.x;
    acc.y += w * v.y;
    acc.z += w * v.z;
    acc.w += w * v.w;
  }
  if (BIAS) {
    float4 bv = ((const float4*)bias)[lane];
    acc.x += bv.x; acc.y += bv.y; acc.z += bv.z; acc.w += bv.w;
  }
  *(float4*)&out[(size_t)row * D + lane * 4] = acc;
}

extern "C" void kernel_launch(void* const* d_in, const int* in_sizes, int n_in,
                              void* d_out, int out_size, void* d_ws, size_t ws_size,
                              hipStream_t stream) {
  const float* x  = (const float*)d_in[0];
  const int*   ei = (const int*)d_in[1];   // [2, E] row-major int32
  const float* ew = (const float*)d_in[2];
  const float* W1 = (const float*)d_in[3];
  const float* b1 = (const float*)d_in[4];
  const float* W2 = (const float*)d_in[5];
  const float* b2 = (const float*)d_in[6];
  float* out = (float*)d_out;

  // workspace layout
  char* p = (char*)d_ws;
  int*   cnt     = (int*)p;                 p += sizeof(int) * NN;
  int*   row_ptr = (int*)p;                 p += sizeof(int) * (NN + 4);
  int*   next    = (int*)p;                 p += sizeof(int) * NN;
  int*   blk_sum = (int*)p;                 p += sizeof(int) * (NBLK + 1);
  int*   blk_off = (int*)p;                 p += sizeof(int) * (NBLK + 1);
  int*   col     = (int*)p;                 p += sizeof(int) * NE;
  float* wv      = (float*)p;               p += sizeof(float) * NE;
  float* h0      = (float*)p;               p += sizeof(float) * (size_t)NN * DIN;
  float* acc1    = (float*)p;               // [NN, DIN]
  float* h2      = h0;                      // reuse h0 region after spmm1

  // CSR build (shared by both layers)
  hipMemsetAsync(cnt, 0, sizeof(int) * NN, stream);
  hist_kernel<<<(NE + 255) / 256, 256, 0, stream>>>(ei, cnt);
  scan_local_kernel<<<NBLK, 256, 0, stream>>>(cnt, row_ptr, blk_sum);
  scan_blk_kernel<<<1, 512, 0, stream>>>(blk_sum, blk_off);
  scan_add_kernel<<<NBLK, 256, 0, stream>>>(row_ptr, blk_off, next);
  scatter_kernel<<<(NE + 255) / 256, 256, 0, stream>>>(ei, ew, next, col, wv);

  // layer 1
  gemm1_kernel<<<(NN + G1_BM - 1) / G1_BM, 256, 0, stream>>>(x, W1, h0);
  spmm_gather_kernel<DIN, 32, false>
      <<<(NN * 32 + 255) / 256, 256, 0, stream>>>(row_ptr, col, wv, h0, nullptr, acc1);

  // layer 2
  gemm2_kernel<<<(NN + 63) / 64, 256, 0, stream>>>(acc1, b1, W2, h2);
  spmm_gather_kernel<DOUT, 16, true>
      <<<(NN * 16 + 255) / 256, 256, 0, stream>>>(row_ptr, col, wv, h2, b2, out);
}

// Round 7
// 316.352 us; speedup vs baseline: 1.2623x; 1.1500x over previous
//
#include <hip/hip_runtime.h>

#define NN 100000
#define NE 600000
#define DIN 128
#define DOUT 64
#define SCAN_B 256
#define NBLK ((NN + SCAN_B - 1) / SCAN_B)  // 391

typedef __attribute__((ext_vector_type(8))) short bf16x8;
typedef __attribute__((ext_vector_type(4))) short s16x4;
typedef __attribute__((ext_vector_type(4))) float f32x4;

__device__ inline short f2bf(float f) {  // RTN-even fp32 -> bf16 bits
  union { float f; unsigned u; } v; v.f = f;
  unsigned r = (v.u + 0x7FFF + ((v.u >> 16) & 1)) >> 16;
  return (short)r;
}
__device__ inline float bf2f(unsigned short u) {
  union { unsigned u; float f; } v; v.u = ((unsigned)u) << 16;
  return v.f;
}

// ---------------- CSR build ----------------
__global__ __launch_bounds__(256) void hist_kernel(const int* __restrict__ ei,
                                                   int* __restrict__ cnt) {
  int e = blockIdx.x * 256 + threadIdx.x;
  if (e < NE) atomicAdd(&cnt[ei[NE + e]], 1);
}

__global__ __launch_bounds__(256) void scan_local_kernel(const int* __restrict__ cnt,
                                                         int* __restrict__ row_ptr,
                                                         int* __restrict__ blk_sum) {
  __shared__ int s[256];
  const int b = blockIdx.x, t = threadIdx.x;
  const int i = b * 256 + t;
  int v = (i < NN) ? cnt[i] : 0;
  s[t] = v;
  __syncthreads();
  for (int off = 1; off < 256; off <<= 1) {
    int u = (t >= off) ? s[t - off] : 0;
    __syncthreads();
    s[t] += u;
    __syncthreads();
  }
  if (i < NN) row_ptr[i] = s[t] - v;
  if (t == 255) blk_sum[b] = s[255];
}

__global__ __launch_bounds__(512) void scan_blk_kernel(const int* __restrict__ blk_sum,
                                                       int* __restrict__ blk_off) {
  __shared__ int s[512];
  const int t = threadIdx.x;
  int v = (t < NBLK) ? blk_sum[t] : 0;
  s[t] = v;
  __syncthreads();
  for (int off = 1; off < 512; off <<= 1) {
    int u = (t >= off) ? s[t - off] : 0;
    __syncthreads();
    s[t] += u;
    __syncthreads();
  }
  if (t < NBLK) blk_off[t] = s[t] - v;
}

// writes next[] (aliased onto cnt[], which is dead after scan_local)
__global__ __launch_bounds__(256) void scan_add_kernel(int* __restrict__ row_ptr,
                                                       const int* __restrict__ blk_off,
                                                       int* __restrict__ next) {
  const int b = blockIdx.x, t = threadIdx.x;
  const int i = b * 256 + t;
  if (i < NN) {
    int v = row_ptr[i] + blk_off[b];
    row_ptr[i] = v;
    next[i] = v;
  }
  if (i == 0) row_ptr[NN] = NE;
}

__global__ __launch_bounds__(256) void scatter_kernel(const int* __restrict__ ei,
                                                      const float* __restrict__ ew,
                                                      int* __restrict__ next,
                                                      int* __restrict__ col,
                                                      float* __restrict__ wv) {
  int e = blockIdx.x * 256 + threadIdx.x;
  if (e >= NE) return;
  int src = ei[e];
  int dst = ei[NE + e];
  int pos = atomicAdd(&next[dst], 1);
  col[pos] = src;
  wv[pos] = ew[e];
}

// ---------------- prep: W1^T as bf16 (tiny, once per call) ------------------
__global__ __launch_bounds__(256) void prep_w1t_kernel(const float* __restrict__ W1,
                                                       short* __restrict__ w1t) {
  int i = blockIdx.x * 256 + threadIdx.x;  // 16384 elements
  if (i < DIN * DIN) {
    int n = i >> 7, k = i & 127;
    w1t[i] = f2bf(W1[k * DIN + n]);  // w1t[n][k]
  }
}

// ---------------- GEMM1 via MFMA bf16: h0(bf16) = x @ W1 --------------------
// Block = 128x128, 4 waves. x tile fp32->bf16 into padded LDS; A via
// ds_read_b128; B via 16B global loads from L1-resident W1^T (32 KB).
// C/D: col=lane&15, row=quad*4+reg. Output stored as bf16.
#define G1_BM 128
#define XS_PITCH 136
__global__ __launch_bounds__(256) void gemm1_mfma_kernel(const float* __restrict__ x,
                                                         const short* __restrict__ w1t,
                                                         short* __restrict__ h0) {
  __shared__ short xs[G1_BM][XS_PITCH];  // ~34 KB
  const int t = threadIdx.x;
  const int row0 = blockIdx.x * G1_BM;
#pragma unroll
  for (int i = 0; i < 16; ++i) {
    int f = t + i * 256;
    int r = f >> 5, c4 = f & 31;
    int gr = row0 + r;
    float4 v = (gr < NN) ? *(const float4*)&x[(size_t)gr * DIN + c4 * 4]
                         : make_float4(0.f, 0.f, 0.f, 0.f);
    s16x4 s;
    s.x = f2bf(v.x); s.y = f2bf(v.y); s.z = f2bf(v.z); s.w = f2bf(v.w);
    *(s16x4*)&xs[r][c4 * 4] = s;
  }
  __syncthreads();

  const int wave = t >> 6, lane = t & 63;
  const int nlane = lane & 15, quad = lane >> 4;
  const int mbase = wave * 32;
  f32x4 acc[2][8];
#pragma unroll
  for (int mt = 0; mt < 2; ++mt)
#pragma unroll
    for (int nt = 0; nt < 8; ++nt) acc[mt][nt] = (f32x4){0.f, 0.f, 0.f, 0.f};

#pragma unroll
  for (int ks = 0; ks < 4; ++ks) {
    const int koff = ks * 32 + quad * 8;
    bf16x8 a0 = *(const bf16x8*)&xs[mbase + nlane][koff];
    bf16x8 a1 = *(const bf16x8*)&xs[mbase + 16 + nlane][koff];
#pragma unroll
    for (int nt = 0; nt < 8; ++nt) {
      bf16x8 b = *(const bf16x8*)&w1t[(size_t)(nt * 16 + nlane) * DIN + koff];
      acc[0][nt] = __builtin_amdgcn_mfma_f32_16x16x32_bf16(a0, b, acc[0][nt], 0, 0, 0);
      acc[1][nt] = __builtin_amdgcn_mfma_f32_16x16x32_bf16(a1, b, acc[1][nt], 0, 0, 0);
    }
  }

#pragma unroll
  for (int mt = 0; mt < 2; ++mt)
#pragma unroll
    for (int nt = 0; nt < 8; ++nt)
#pragma unroll
      for (int rg = 0; rg < 4; ++rg) {
        int gr = row0 + mbase + mt * 16 + quad * 4 + rg;
        if (gr < NN) h0[(size_t)gr * DIN + nt * 16 + nlane] = f2bf(acc[mt][nt][rg]);
      }
}

// ---------------- GEMM2: h2(bf16) = relu(h1 + b1) @ W2, BM=64 ---------------
__global__ __launch_bounds__(256) void gemm2_kernel(const float* __restrict__ h1,
                                                    const float* __restrict__ b1,
                                                    const float* __restrict__ W2,
                                                    short* __restrict__ h2) {
  __shared__ float xs[64][DIN];
  const int t = threadIdx.x;
  const int row0 = blockIdx.x * 64;
#pragma unroll
  for (int i = 0; i < 8; ++i) {
    int f = t + i * 256;
    int r = f >> 5, c4 = f & 31;
    int gr = row0 + r;
    float4 v;
    if (gr < NN) {
      v = *(const float4*)&h1[(size_t)gr * DIN + c4 * 4];
      float4 b = *(const float4*)&b1[c4 * 4];
      v.x = fmaxf(v.x + b.x, 0.f);
      v.y = fmaxf(v.y + b.y, 0.f);
      v.z = fmaxf(v.z + b.z, 0.f);
      v.w = fmaxf(v.w + b.w, 0.f);
    } else {
      v = make_float4(0.f, 0.f, 0.f, 0.f);
    }
    *(float4*)&xs[r][c4 * 4] = v;
  }
  __syncthreads();
  const int j0 = (t & 15) * 4;
  const int r0 = (t >> 4) * 4;
  float4 acc[4];
#pragma unroll
  for (int i = 0; i < 4; ++i) acc[i] = make_float4(0.f, 0.f, 0.f, 0.f);
  for (int k0 = 0; k0 < DIN; k0 += 4) {
    float4 w[4];
#pragma unroll
    for (int kk = 0; kk < 4; ++kk) w[kk] = *(const float4*)&W2[(k0 + kk) * DOUT + j0];
#pragma unroll
    for (int i = 0; i < 4; ++i) {
      float4 xr = *(const float4*)&xs[r0 + i][k0];
      acc[i].x += xr.x * w[0].x + xr.y * w[1].x + xr.z * w[2].x + xr.w * w[3].x;
      acc[i].y += xr.x * w[0].y + xr.y * w[1].y + xr.z * w[2].y + xr.w * w[3].y;
      acc[i].z += xr.x * w[0].z + xr.y * w[1].z + xr.z * w[2].z + xr.w * w[3].z;
      acc[i].w += xr.x * w[0].w + xr.y * w[1].w + xr.z * w[2].w + xr.w * w[3].w;
    }
  }
#pragma unroll
  for (int i = 0; i < 4; ++i) {
    int gr = row0 + r0 + i;
    if (gr < NN) {
      ushort4 s;
      s.x = (unsigned short)f2bf(acc[i].x);
      s.y = (unsigned short)f2bf(acc[i].y);
      s.z = (unsigned short)f2bf(acc[i].z);
      s.w = (unsigned short)f2bf(acc[i].w);
      *(ushort4*)&h2[(size_t)gr * DOUT + j0] = s;
    }
  }
}

// ------- gather SpMM, bf16 h: out[r] = sum w_e * h[col[e]] (+bias) ----------
template <int D, int LPE, bool BIAS>
__global__ __launch_bounds__(256) void spmm_gather_bf16_kernel(
    const int* __restrict__ rp, const int* __restrict__ col,
    const float* __restrict__ wv, const short* __restrict__ h,
    const float* __restrict__ bias, float* __restrict__ out) {
  const int row = blockIdx.x * (256 / LPE) + threadIdx.x / LPE;
  const int lane = threadIdx.x % LPE;
  if (row >= NN) return;
  const int b = rp[row], e = rp[row + 1];
  float4 acc = make_float4(0.f, 0.f, 0.f, 0.f);
  for (int i = b; i < e; ++i) {
    int s = col[i];
    float w = wv[i];
    ushort4 v = *(const ushort4*)&h[(size_t)s * D + lane * 4];
    acc.x += w * bf2f(v.x);
    acc.y += w * bf2f(v.y);
    acc.z += w * bf2f(v.z);
    acc.w += w * bf2f(v.w);
  }
  if (BIAS) {
    float4 bv = ((const float4*)bias)[lane];
    acc.x += bv.x; acc.y += bv.y; acc.z += bv.z; acc.w += bv.w;
  }
  *(float4*)&out[(size_t)row * D + lane * 4] = acc;
}

extern "C" void kernel_launch(void* const* d_in, const int* in_sizes, int n_in,
                              void* d_out, int out_size, void* d_ws, size_t ws_size,
                              hipStream_t stream) {
  const float* x  = (const float*)d_in[0];
  const int*   ei = (const int*)d_in[1];
  const float* ew = (const float*)d_in[2];
  const float* W1 = (const float*)d_in[3];
  const float* b1 = (const float*)d_in[4];
  const float* W2 = (const float*)d_in[5];
  const float* b2 = (const float*)d_in[6];
  float* out = (float*)d_out;

  // workspace layout — total ~82.4 MB (round-5's 108.4 MB provably overflowed
  // once w1t pushed it +32 KB: post-timing corruption of pristine inputs)
  char* p = (char*)d_ws;
  int*   cnt     = (int*)p;                 p += sizeof(int) * NN;       // reused as `next`
  int*   row_ptr = (int*)p;                 p += sizeof(int) * (NN + 4);
  int*   blk_sum = (int*)p;                 p += sizeof(int) * (NBLK + 1);
  int*   blk_off = (int*)p;                 p += sizeof(int) * (NBLK + 1);
  int*   col     = (int*)p;                 p += sizeof(int) * NE;
  float* wv      = (float*)p;               p += sizeof(float) * NE;
  short* w1t     = (short*)p;               p += sizeof(short) * DIN * DIN;
  short* h0      = (short*)p;               p += sizeof(short) * (size_t)NN * DIN;  // bf16
  float* acc1    = (float*)p;               // [NN, DIN] fp32
  int*   next    = cnt;                     // cnt dead after scan_local
  short* h2      = h0;                      // h0 dead after spmm1; [NN, DOUT] bf16

  // CSR build (shared by both layers)
  hipMemsetAsync(cnt, 0, sizeof(int) * NN, stream);
  hist_kernel<<<(NE + 255) / 256, 256, 0, stream>>>(ei, cnt);
  scan_local_kernel<<<NBLK, 256, 0, stream>>>(cnt, row_ptr, blk_sum);
  scan_blk_kernel<<<1, 512, 0, stream>>>(blk_sum, blk_off);
  scan_add_kernel<<<NBLK, 256, 0, stream>>>(row_ptr, blk_off, next);
  scatter_kernel<<<(NE + 255) / 256, 256, 0, stream>>>(ei, ew, next, col, wv);

  // layer 1
  prep_w1t_kernel<<<(DIN * DIN + 255) / 256, 256, 0, stream>>>(W1, w1t);
  gemm1_mfma_kernel<<<(NN + G1_BM - 1) / G1_BM, 256, 0, stream>>>(x, w1t, h0);
  spmm_gather_bf16_kernel<DIN, 32, false>
      <<<(NN * 32 + 255) / 256, 256, 0, stream>>>(row_ptr, col, wv, h0, nullptr, acc1);

  // layer 2
  gemm2_kernel<<<(NN + 63) / 64, 256, 0, stream>>>(acc1, b1, W2, h2);
  spmm_gather_bf16_kernel<DOUT, 16, true>
      <<<(NN * 16 + 255) / 256, 256, 0, stream>>>(row_ptr, col, wv, h2, b2, out);
}

// Round 8
// 276.533 us; speedup vs baseline: 1.4441x; 1.1440x over previous
//
#include <hip/hip_runtime.h>

#define NN 100000
#define NE 600000
#define DIN 128
#define DOUT 64
#define SCAN_B 256
#define NBLK ((NN + SCAN_B - 1) / SCAN_B)  // 391
#define HIST_B ((NE + 255) / 256)          // 2344
#define PREP_N (DIN * DIN + DIN * DOUT)    // 24576
#define PREP_B ((PREP_N + 255) / 256)      // 96

typedef __attribute__((ext_vector_type(8))) short bf16x8;
typedef __attribute__((ext_vector_type(4))) short s16x4;
typedef __attribute__((ext_vector_type(4))) float f32x4;

__device__ inline short f2bf(float f) {  // RTN-even fp32 -> bf16 bits
  union { float f; unsigned u; } v; v.f = f;
  unsigned r = (v.u + 0x7FFF + ((v.u >> 16) & 1)) >> 16;
  return (short)r;
}
__device__ inline float bf2f(unsigned short u) {
  union { unsigned u; float f; } v; v.u = ((unsigned)u) << 16;
  return v.f;
}

// ------- hist (+ fused W1^T / W2^T bf16 prep via grid split) ----------------
__global__ __launch_bounds__(256) void hist_prep_kernel(const int* __restrict__ ei,
                                                        int* __restrict__ cnt,
                                                        const float* __restrict__ W1,
                                                        short* __restrict__ w1t,
                                                        const float* __restrict__ W2,
                                                        short* __restrict__ w2t) {
  const int b = blockIdx.x, t = threadIdx.x;
  if (b < HIST_B) {
    int e = b * 256 + t;
    if (e < NE) atomicAdd(&cnt[ei[NE + e]], 1);
  } else {
    int i = (b - HIST_B) * 256 + t;
    if (i < DIN * DIN) {
      int n = i >> 7, k = i & 127;
      w1t[i] = f2bf(W1[k * DIN + n]);            // w1t[n][k]
    } else if (i < PREP_N) {
      int i2 = i - DIN * DIN;
      int n = i2 >> 7, k = i2 & 127;
      w2t[i2] = f2bf(W2[k * DOUT + n]);          // w2t[n][k]
    }
  }
}

__global__ __launch_bounds__(256) void scan_local_kernel(const int* __restrict__ cnt,
                                                         int* __restrict__ row_ptr,
                                                         int* __restrict__ blk_sum) {
  __shared__ int s[256];
  const int b = blockIdx.x, t = threadIdx.x;
  const int i = b * 256 + t;
  int v = (i < NN) ? cnt[i] : 0;
  s[t] = v;
  __syncthreads();
  for (int off = 1; off < 256; off <<= 1) {
    int u = (t >= off) ? s[t - off] : 0;
    __syncthreads();
    s[t] += u;
    __syncthreads();
  }
  if (i < NN) row_ptr[i] = s[t] - v;
  if (t == 255) blk_sum[b] = s[255];
}

__global__ __launch_bounds__(512) void scan_blk_kernel(const int* __restrict__ blk_sum,
                                                       int* __restrict__ blk_off) {
  __shared__ int s[512];
  const int t = threadIdx.x;
  int v = (t < NBLK) ? blk_sum[t] : 0;
  s[t] = v;
  __syncthreads();
  for (int off = 1; off < 512; off <<= 1) {
    int u = (t >= off) ? s[t - off] : 0;
    __syncthreads();
    s[t] += u;
    __syncthreads();
  }
  if (t < NBLK) blk_off[t] = s[t] - v;
}

__global__ __launch_bounds__(256) void scan_add_kernel(int* __restrict__ row_ptr,
                                                       const int* __restrict__ blk_off,
                                                       int* __restrict__ next) {
  const int b = blockIdx.x, t = threadIdx.x;
  const int i = b * 256 + t;
  if (i < NN) {
    int v = row_ptr[i] + blk_off[b];
    row_ptr[i] = v;
    next[i] = v;
  }
  if (i == 0) row_ptr[NN] = NE;
}

__global__ __launch_bounds__(256) void scatter_kernel(const int* __restrict__ ei,
                                                      const float* __restrict__ ew,
                                                      int* __restrict__ next,
                                                      int* __restrict__ col,
                                                      float* __restrict__ wv) {
  int e = blockIdx.x * 256 + threadIdx.x;
  if (e >= NE) return;
  int src = ei[e];
  int dst = ei[NE + e];
  int pos = atomicAdd(&next[dst], 1);
  col[pos] = src;
  wv[pos] = ew[e];
}

// ---------------- GEMM1 via MFMA bf16: h0(bf16) = x @ W1 (proven r7) --------
#define G1_BM 128
#define XS_PITCH 136
__global__ __launch_bounds__(256) void gemm1_mfma_kernel(const float* __restrict__ x,
                                                         const short* __restrict__ w1t,
                                                         short* __restrict__ h0) {
  __shared__ short xs[G1_BM][XS_PITCH];
  const int t = threadIdx.x;
  const int row0 = blockIdx.x * G1_BM;
#pragma unroll
  for (int i = 0; i < 16; ++i) {
    int f = t + i * 256;
    int r = f >> 5, c4 = f & 31;
    int gr = row0 + r;
    float4 v = (gr < NN) ? *(const float4*)&x[(size_t)gr * DIN + c4 * 4]
                         : make_float4(0.f, 0.f, 0.f, 0.f);
    s16x4 s;
    s.x = f2bf(v.x); s.y = f2bf(v.y); s.z = f2bf(v.z); s.w = f2bf(v.w);
    *(s16x4*)&xs[r][c4 * 4] = s;
  }
  __syncthreads();

  const int wave = t >> 6, lane = t & 63;
  const int nlane = lane & 15, quad = lane >> 4;
  const int mbase = wave * 32;
  f32x4 acc[2][8];
#pragma unroll
  for (int mt = 0; mt < 2; ++mt)
#pragma unroll
    for (int nt = 0; nt < 8; ++nt) acc[mt][nt] = (f32x4){0.f, 0.f, 0.f, 0.f};

#pragma unroll
  for (int ks = 0; ks < 4; ++ks) {
    const int koff = ks * 32 + quad * 8;
    bf16x8 a0 = *(const bf16x8*)&xs[mbase + nlane][koff];
    bf16x8 a1 = *(const bf16x8*)&xs[mbase + 16 + nlane][koff];
#pragma unroll
    for (int nt = 0; nt < 8; ++nt) {
      bf16x8 b = *(const bf16x8*)&w1t[(size_t)(nt * 16 + nlane) * DIN + koff];
      acc[0][nt] = __builtin_amdgcn_mfma_f32_16x16x32_bf16(a0, b, acc[0][nt], 0, 0, 0);
      acc[1][nt] = __builtin_amdgcn_mfma_f32_16x16x32_bf16(a1, b, acc[1][nt], 0, 0, 0);
    }
  }

#pragma unroll
  for (int mt = 0; mt < 2; ++mt)
#pragma unroll
    for (int nt = 0; nt < 8; ++nt)
#pragma unroll
      for (int rg = 0; rg < 4; ++rg) {
        int gr = row0 + mbase + mt * 16 + quad * 4 + rg;
        if (gr < NN) h0[(size_t)gr * DIN + nt * 16 + nlane] = f2bf(acc[mt][nt][rg]);
      }
}

// -------- GEMM2 via MFMA bf16: h2(bf16) = relu(acc1 + b1) @ W2 --------------
// Same structure as gemm1, N=64 (4 n-tiles); staging fuses bias+relu+cvt.
__global__ __launch_bounds__(256) void gemm2_mfma_kernel(const float* __restrict__ acc1,
                                                         const float* __restrict__ b1,
                                                         const short* __restrict__ w2t,
                                                         short* __restrict__ h2) {
  __shared__ short xs[G1_BM][XS_PITCH];
  const int t = threadIdx.x;
  const int row0 = blockIdx.x * G1_BM;
#pragma unroll
  for (int i = 0; i < 16; ++i) {
    int f = t + i * 256;
    int r = f >> 5, c4 = f & 31;
    int gr = row0 + r;
    float4 v = (gr < NN) ? *(const float4*)&acc1[(size_t)gr * DIN + c4 * 4]
                         : make_float4(0.f, 0.f, 0.f, 0.f);
    float4 bb = *(const float4*)&b1[c4 * 4];
    s16x4 s;
    s.x = f2bf(fmaxf(v.x + bb.x, 0.f));
    s.y = f2bf(fmaxf(v.y + bb.y, 0.f));
    s.z = f2bf(fmaxf(v.z + bb.z, 0.f));
    s.w = f2bf(fmaxf(v.w + bb.w, 0.f));
    *(s16x4*)&xs[r][c4 * 4] = s;
  }
  __syncthreads();

  const int wave = t >> 6, lane = t & 63;
  const int nlane = lane & 15, quad = lane >> 4;
  const int mbase = wave * 32;
  f32x4 acc[2][4];
#pragma unroll
  for (int mt = 0; mt < 2; ++mt)
#pragma unroll
    for (int nt = 0; nt < 4; ++nt) acc[mt][nt] = (f32x4){0.f, 0.f, 0.f, 0.f};

#pragma unroll
  for (int ks = 0; ks < 4; ++ks) {
    const int koff = ks * 32 + quad * 8;
    bf16x8 a0 = *(const bf16x8*)&xs[mbase + nlane][koff];
    bf16x8 a1 = *(const bf16x8*)&xs[mbase + 16 + nlane][koff];
#pragma unroll
    for (int nt = 0; nt < 4; ++nt) {
      bf16x8 b = *(const bf16x8*)&w2t[(size_t)(nt * 16 + nlane) * DIN + koff];
      acc[0][nt] = __builtin_amdgcn_mfma_f32_16x16x32_bf16(a0, b, acc[0][nt], 0, 0, 0);
      acc[1][nt] = __builtin_amdgcn_mfma_f32_16x16x32_bf16(a1, b, acc[1][nt], 0, 0, 0);
    }
  }

#pragma unroll
  for (int mt = 0; mt < 2; ++mt)
#pragma unroll
    for (int nt = 0; nt < 4; ++nt)
#pragma unroll
      for (int rg = 0; rg < 4; ++rg) {
        int gr = row0 + mbase + mt * 16 + quad * 4 + rg;
        if (gr < NN) h2[(size_t)gr * DOUT + nt * 16 + nlane] = f2bf(acc[mt][nt][rg]);
      }
}

// ------- gather SpMM, bf16 h, 16B/lane, edge-loop unrolled x2 ---------------
template <int D, int LPE, bool BIAS>
__global__ __launch_bounds__(256) void spmm_gather_bf16_kernel(
    const int* __restrict__ rp, const int* __restrict__ col,
    const float* __restrict__ wv, const short* __restrict__ h,
    const float* __restrict__ bias, float* __restrict__ out) {
  const int row = blockIdx.x * (256 / LPE) + threadIdx.x / LPE;
  const int lane = threadIdx.x % LPE;  // owns elements [lane*8, lane*8+8)
  if (row >= NN) return;
  const int b = rp[row], e = rp[row + 1];
  float acc[8];
#pragma unroll
  for (int j = 0; j < 8; ++j) acc[j] = 0.f;
  int i = b;
  for (; i + 2 <= e; i += 2) {
    int s0 = col[i], s1 = col[i + 1];
    float w0 = wv[i], w1 = wv[i + 1];
    bf16x8 v0 = *(const bf16x8*)&h[(size_t)s0 * D + lane * 8];
    bf16x8 v1 = *(const bf16x8*)&h[(size_t)s1 * D + lane * 8];
#pragma unroll
    for (int j = 0; j < 8; ++j)
      acc[j] += w0 * bf2f((unsigned short)v0[j]) + w1 * bf2f((unsigned short)v1[j]);
  }
  if (i < e) {
    int s0 = col[i];
    float w0 = wv[i];
    bf16x8 v0 = *(const bf16x8*)&h[(size_t)s0 * D + lane * 8];
#pragma unroll
    for (int j = 0; j < 8; ++j) acc[j] += w0 * bf2f((unsigned short)v0[j]);
  }
  if (BIAS) {
#pragma unroll
    for (int j = 0; j < 8; ++j) acc[j] += bias[lane * 8 + j];
  }
  float4 o0 = make_float4(acc[0], acc[1], acc[2], acc[3]);
  float4 o1 = make_float4(acc[4], acc[5], acc[6], acc[7]);
  *(float4*)&out[(size_t)row * D + lane * 8] = o0;
  *(float4*)&out[(size_t)row * D + lane * 8 + 4] = o1;
}

extern "C" void kernel_launch(void* const* d_in, const int* in_sizes, int n_in,
                              void* d_out, int out_size, void* d_ws, size_t ws_size,
                              hipStream_t stream) {
  const float* x  = (const float*)d_in[0];
  const int*   ei = (const int*)d_in[1];
  const float* ew = (const float*)d_in[2];
  const float* W1 = (const float*)d_in[3];
  const float* b1 = (const float*)d_in[4];
  const float* W2 = (const float*)d_in[5];
  const float* b2 = (const float*)d_in[6];
  float* out = (float*)d_out;

  // workspace layout — ~82.5 MB (82.4 MB proven safe in round 7)
  char* p = (char*)d_ws;
  int*   cnt     = (int*)p;                 p += sizeof(int) * NN;       // reused as `next`
  int*   row_ptr = (int*)p;                 p += sizeof(int) * (NN + 4);
  int*   blk_sum = (int*)p;                 p += sizeof(int) * (NBLK + 1);
  int*   blk_off = (int*)p;                 p += sizeof(int) * (NBLK + 1);
  int*   col     = (int*)p;                 p += sizeof(int) * NE;
  float* wv      = (float*)p;               p += sizeof(float) * NE;
  short* w1t     = (short*)p;               p += sizeof(short) * DIN * DIN;
  short* w2t     = (short*)p;               p += sizeof(short) * DIN * DOUT;
  short* h0      = (short*)p;               p += sizeof(short) * (size_t)NN * DIN;  // bf16
  float* acc1    = (float*)p;               // [NN, DIN] fp32
  int*   next    = cnt;                     // cnt dead after scan_local
  short* h2      = h0;                      // h0 dead after spmm1; [NN, DOUT] bf16

  // CSR build + weight prep
  hipMemsetAsync(cnt, 0, sizeof(int) * NN, stream);
  hist_prep_kernel<<<HIST_B + PREP_B, 256, 0, stream>>>(ei, cnt, W1, w1t, W2, w2t);
  scan_local_kernel<<<NBLK, 256, 0, stream>>>(cnt, row_ptr, blk_sum);
  scan_blk_kernel<<<1, 512, 0, stream>>>(blk_sum, blk_off);
  scan_add_kernel<<<NBLK, 256, 0, stream>>>(row_ptr, blk_off, next);
  scatter_kernel<<<HIST_B, 256, 0, stream>>>(ei, ew, next, col, wv);

  // layer 1
  gemm1_mfma_kernel<<<(NN + G1_BM - 1) / G1_BM, 256, 0, stream>>>(x, w1t, h0);
  spmm_gather_bf16_kernel<DIN, 16, false>
      <<<(NN * 16 + 255) / 256, 256, 0, stream>>>(row_ptr, col, wv, h0, nullptr, acc1);

  // layer 2
  gemm2_mfma_kernel<<<(NN + G1_BM - 1) / G1_BM, 256, 0, stream>>>(acc1, b1, w2t, h2);
  spmm_gather_bf16_kernel<DOUT, 8, true>
      <<<(NN * 8 + 255) / 256, 256, 0, stream>>>(row_ptr, col, wv, h2, b2, out);
}

// Round 9
// 261.655 us; speedup vs baseline: 1.5262x; 1.0569x over previous
//
#include <hip/hip_runtime.h>

#define NN 100000
#define NE 600000
#define DIN 128
#define DOUT 64
#define SCAN_B 256
#define NBLK ((NN + SCAN_B - 1) / SCAN_B)  // 391
#define HIST_B ((NE + 255) / 256)          // 2344
#define PREP_N (DIN * DIN + DIN * DOUT)    // 24576
#define PREP_B ((PREP_N + 255) / 256)      // 96

typedef __attribute__((ext_vector_type(8))) short bf16x8;
typedef __attribute__((ext_vector_type(4))) short s16x4;
typedef __attribute__((ext_vector_type(4))) float f32x4;

__device__ inline short f2bf(float f) {  // RTN-even fp32 -> bf16 bits
  union { float f; unsigned u; } v; v.f = f;
  unsigned r = (v.u + 0x7FFF + ((v.u >> 16) & 1)) >> 16;
  return (short)r;
}
__device__ inline float bf2f(unsigned short u) {
  union { unsigned u; float f; } v; v.u = ((unsigned)u) << 16;
  return v.f;
}

// ------- hist (+ fused W1^T / W2^T bf16 prep via grid split) ----------------
__global__ __launch_bounds__(256) void hist_prep_kernel(const int* __restrict__ ei,
                                                        int* __restrict__ cnt,
                                                        const float* __restrict__ W1,
                                                        short* __restrict__ w1t,
                                                        const float* __restrict__ W2,
                                                        short* __restrict__ w2t) {
  const int b = blockIdx.x, t = threadIdx.x;
  if (b < HIST_B) {
    int e = b * 256 + t;
    if (e < NE) atomicAdd(&cnt[ei[NE + e]], 1);
  } else {
    int i = (b - HIST_B) * 256 + t;
    if (i < DIN * DIN) {
      int n = i >> 7, k = i & 127;
      w1t[i] = f2bf(W1[k * DIN + n]);            // w1t[n][k]
    } else if (i < PREP_N) {
      int i2 = i - DIN * DIN;
      int n = i2 >> 7, k = i2 & 127;
      w2t[i2] = f2bf(W2[k * DOUT + n]);          // w2t[n][k]
    }
  }
}

__global__ __launch_bounds__(256) void scan_local_kernel(const int* __restrict__ cnt,
                                                         int* __restrict__ row_ptr,
                                                         int* __restrict__ blk_sum) {
  __shared__ int s[256];
  const int b = blockIdx.x, t = threadIdx.x;
  const int i = b * 256 + t;
  int v = (i < NN) ? cnt[i] : 0;
  s[t] = v;
  __syncthreads();
  for (int off = 1; off < 256; off <<= 1) {
    int u = (t >= off) ? s[t - off] : 0;
    __syncthreads();
    s[t] += u;
    __syncthreads();
  }
  if (i < NN) row_ptr[i] = s[t] - v;
  if (t == 255) blk_sum[b] = s[255];
}

__global__ __launch_bounds__(512) void scan_blk_kernel(const int* __restrict__ blk_sum,
                                                       int* __restrict__ blk_off) {
  __shared__ int s[512];
  const int t = threadIdx.x;
  int v = (t < NBLK) ? blk_sum[t] : 0;
  s[t] = v;
  __syncthreads();
  for (int off = 1; off < 512; off <<= 1) {
    int u = (t >= off) ? s[t - off] : 0;
    __syncthreads();
    s[t] += u;
    __syncthreads();
  }
  if (t < NBLK) blk_off[t] = s[t] - v;
}

__global__ __launch_bounds__(256) void scan_add_kernel(int* __restrict__ row_ptr,
                                                       const int* __restrict__ blk_off,
                                                       int* __restrict__ next) {
  const int b = blockIdx.x, t = threadIdx.x;
  const int i = b * 256 + t;
  if (i < NN) {
    int v = row_ptr[i] + blk_off[b];
    row_ptr[i] = v;
    next[i] = v;
  }
  if (i == 0) row_ptr[NN] = NE;
}

// one 8B (src, w) write per edge instead of two 4B writes
__global__ __launch_bounds__(256) void scatter_kernel(const int* __restrict__ ei,
                                                      const float* __restrict__ ew,
                                                      int* __restrict__ next,
                                                      int2* __restrict__ ep) {
  int e = blockIdx.x * 256 + threadIdx.x;
  if (e >= NE) return;
  int src = ei[e];
  int dst = ei[NE + e];
  int pos = atomicAdd(&next[dst], 1);
  ep[pos] = make_int2(src, __float_as_int(ew[e]));
}

// ---------------- GEMM1 via MFMA bf16: h0(bf16) = x @ W1 (proven r7/r8) -----
#define G1_BM 128
#define XS_PITCH 136
__global__ __launch_bounds__(256) void gemm1_mfma_kernel(const float* __restrict__ x,
                                                         const short* __restrict__ w1t,
                                                         short* __restrict__ h0) {
  __shared__ short xs[G1_BM][XS_PITCH];
  const int t = threadIdx.x;
  const int row0 = blockIdx.x * G1_BM;
#pragma unroll
  for (int i = 0; i < 16; ++i) {
    int f = t + i * 256;
    int r = f >> 5, c4 = f & 31;
    int gr = row0 + r;
    float4 v = (gr < NN) ? *(const float4*)&x[(size_t)gr * DIN + c4 * 4]
                         : make_float4(0.f, 0.f, 0.f, 0.f);
    s16x4 s;
    s.x = f2bf(v.x); s.y = f2bf(v.y); s.z = f2bf(v.z); s.w = f2bf(v.w);
    *(s16x4*)&xs[r][c4 * 4] = s;
  }
  __syncthreads();

  const int wave = t >> 6, lane = t & 63;
  const int nlane = lane & 15, quad = lane >> 4;
  const int mbase = wave * 32;
  f32x4 acc[2][8];
#pragma unroll
  for (int mt = 0; mt < 2; ++mt)
#pragma unroll
    for (int nt = 0; nt < 8; ++nt) acc[mt][nt] = (f32x4){0.f, 0.f, 0.f, 0.f};

#pragma unroll
  for (int ks = 0; ks < 4; ++ks) {
    const int koff = ks * 32 + quad * 8;
    bf16x8 a0 = *(const bf16x8*)&xs[mbase + nlane][koff];
    bf16x8 a1 = *(const bf16x8*)&xs[mbase + 16 + nlane][koff];
#pragma unroll
    for (int nt = 0; nt < 8; ++nt) {
      bf16x8 b = *(const bf16x8*)&w1t[(size_t)(nt * 16 + nlane) * DIN + koff];
      acc[0][nt] = __builtin_amdgcn_mfma_f32_16x16x32_bf16(a0, b, acc[0][nt], 0, 0, 0);
      acc[1][nt] = __builtin_amdgcn_mfma_f32_16x16x32_bf16(a1, b, acc[1][nt], 0, 0, 0);
    }
  }

#pragma unroll
  for (int mt = 0; mt < 2; ++mt)
#pragma unroll
    for (int nt = 0; nt < 8; ++nt)
#pragma unroll
      for (int rg = 0; rg < 4; ++rg) {
        int gr = row0 + mbase + mt * 16 + quad * 4 + rg;
        if (gr < NN) h0[(size_t)gr * DIN + nt * 16 + nlane] = f2bf(acc[mt][nt][rg]);
      }
}

// -------- GEMM2 via MFMA bf16: h2(bf16) = relu(acc1(bf16) + b1) @ W2 --------
__global__ __launch_bounds__(256) void gemm2_mfma_kernel(const short* __restrict__ acc1,
                                                         const float* __restrict__ b1,
                                                         const short* __restrict__ w2t,
                                                         short* __restrict__ h2) {
  __shared__ short xs[G1_BM][XS_PITCH];
  const int t = threadIdx.x;
  const int row0 = blockIdx.x * G1_BM;
  // stage 128x128 bf16 tile with fused bias+relu: 2048 bf16x8 chunks, 8/thread
#pragma unroll
  for (int i = 0; i < 8; ++i) {
    int f = t + i * 256;
    int r = f >> 4, c8 = f & 15;
    int gr = row0 + r;
    bf16x8 v = (gr < NN) ? *(const bf16x8*)&acc1[(size_t)gr * DIN + c8 * 8]
                         : (bf16x8){0, 0, 0, 0, 0, 0, 0, 0};
    bf16x8 s;
#pragma unroll
    for (int j = 0; j < 8; ++j) {
      float fv = bf2f((unsigned short)v[j]) + b1[c8 * 8 + j];
      s[j] = f2bf(fmaxf(fv, 0.f));
    }
    *(bf16x8*)&xs[r][c8 * 8] = s;
  }
  __syncthreads();

  const int wave = t >> 6, lane = t & 63;
  const int nlane = lane & 15, quad = lane >> 4;
  const int mbase = wave * 32;
  f32x4 acc[2][4];
#pragma unroll
  for (int mt = 0; mt < 2; ++mt)
#pragma unroll
    for (int nt = 0; nt < 4; ++nt) acc[mt][nt] = (f32x4){0.f, 0.f, 0.f, 0.f};

#pragma unroll
  for (int ks = 0; ks < 4; ++ks) {
    const int koff = ks * 32 + quad * 8;
    bf16x8 a0 = *(const bf16x8*)&xs[mbase + nlane][koff];
    bf16x8 a1 = *(const bf16x8*)&xs[mbase + 16 + nlane][koff];
#pragma unroll
    for (int nt = 0; nt < 4; ++nt) {
      bf16x8 b = *(const bf16x8*)&w2t[(size_t)(nt * 16 + nlane) * DIN + koff];
      acc[0][nt] = __builtin_amdgcn_mfma_f32_16x16x32_bf16(a0, b, acc[0][nt], 0, 0, 0);
      acc[1][nt] = __builtin_amdgcn_mfma_f32_16x16x32_bf16(a1, b, acc[1][nt], 0, 0, 0);
    }
  }

#pragma unroll
  for (int mt = 0; mt < 2; ++mt)
#pragma unroll
    for (int nt = 0; nt < 4; ++nt)
#pragma unroll
      for (int rg = 0; rg < 4; ++rg) {
        int gr = row0 + mbase + mt * 16 + quad * 4 + rg;
        if (gr < NN) h2[(size_t)gr * DOUT + nt * 16 + nlane] = f2bf(acc[mt][nt][rg]);
      }
}

// ------- gather SpMM, bf16 h, 16B/lane, unroll-4 (4 gather chains) ----------
// OUTBF: write bf16 (layer 1); else fp32 (+bias, layer 2 final output)
template <int D, int LPE, bool BIAS, bool OUTBF>
__global__ __launch_bounds__(256) void spmm_gather_kernel(
    const int* __restrict__ rp, const int2* __restrict__ ep,
    const short* __restrict__ h, const float* __restrict__ bias,
    void* __restrict__ outv) {
  const int row = blockIdx.x * (256 / LPE) + threadIdx.x / LPE;
  const int lane = threadIdx.x % LPE;  // owns elements [lane*8, lane*8+8)
  if (row >= NN) return;
  const int b = rp[row], e = rp[row + 1];
  float acc[8];
#pragma unroll
  for (int j = 0; j < 8; ++j) acc[j] = 0.f;
  int i = b;
  for (; i + 4 <= e; i += 4) {
    int2 p0 = ep[i], p1 = ep[i + 1], p2 = ep[i + 2], p3 = ep[i + 3];
    bf16x8 v0 = *(const bf16x8*)&h[(size_t)p0.x * D + lane * 8];
    bf16x8 v1 = *(const bf16x8*)&h[(size_t)p1.x * D + lane * 8];
    bf16x8 v2 = *(const bf16x8*)&h[(size_t)p2.x * D + lane * 8];
    bf16x8 v3 = *(const bf16x8*)&h[(size_t)p3.x * D + lane * 8];
    float w0 = __int_as_float(p0.y), w1 = __int_as_float(p1.y);
    float w2 = __int_as_float(p2.y), w3 = __int_as_float(p3.y);
#pragma unroll
    for (int j = 0; j < 8; ++j)
      acc[j] += w0 * bf2f((unsigned short)v0[j]) + w1 * bf2f((unsigned short)v1[j]) +
                w2 * bf2f((unsigned short)v2[j]) + w3 * bf2f((unsigned short)v3[j]);
  }
  if (i + 2 <= e) {
    int2 p0 = ep[i], p1 = ep[i + 1];
    bf16x8 v0 = *(const bf16x8*)&h[(size_t)p0.x * D + lane * 8];
    bf16x8 v1 = *(const bf16x8*)&h[(size_t)p1.x * D + lane * 8];
    float w0 = __int_as_float(p0.y), w1 = __int_as_float(p1.y);
#pragma unroll
    for (int j = 0; j < 8; ++j)
      acc[j] += w0 * bf2f((unsigned short)v0[j]) + w1 * bf2f((unsigned short)v1[j]);
    i += 2;
  }
  if (i < e) {
    int2 p0 = ep[i];
    bf16x8 v0 = *(const bf16x8*)&h[(size_t)p0.x * D + lane * 8];
    float w0 = __int_as_float(p0.y);
#pragma unroll
    for (int j = 0; j < 8; ++j) acc[j] += w0 * bf2f((unsigned short)v0[j]);
  }
  if (BIAS) {
#pragma unroll
    for (int j = 0; j < 8; ++j) acc[j] += bias[lane * 8 + j];
  }
  if (OUTBF) {
    bf16x8 o;
#pragma unroll
    for (int j = 0; j < 8; ++j) o[j] = f2bf(acc[j]);
    *(bf16x8*)((short*)outv + (size_t)row * D + lane * 8) = o;
  } else {
    float* out = (float*)outv;
    *(float4*)&out[(size_t)row * D + lane * 8] = make_float4(acc[0], acc[1], acc[2], acc[3]);
    *(float4*)&out[(size_t)row * D + lane * 8 + 4] = make_float4(acc[4], acc[5], acc[6], acc[7]);
  }
}

extern "C" void kernel_launch(void* const* d_in, const int* in_sizes, int n_in,
                              void* d_out, int out_size, void* d_ws, size_t ws_size,
                              hipStream_t stream) {
  const float* x  = (const float*)d_in[0];
  const int*   ei = (const int*)d_in[1];
  const float* ew = (const float*)d_in[2];
  const float* W1 = (const float*)d_in[3];
  const float* b1 = (const float*)d_in[4];
  const float* W2 = (const float*)d_in[5];
  const float* b2 = (const float*)d_in[6];
  float* out = (float*)d_out;

  // workspace layout — ~56.9 MB (82.4 MB proven safe; extra margin)
  char* p = (char*)d_ws;
  int*   cnt     = (int*)p;                 p += sizeof(int) * NN;       // reused as `next`
  int*   row_ptr = (int*)p;                 p += sizeof(int) * (NN + 4);
  int*   blk_sum = (int*)p;                 p += sizeof(int) * (NBLK + 1);
  int*   blk_off = (int*)p;                 p += sizeof(int) * (NBLK + 1);
  int2*  ep      = (int2*)p;                p += sizeof(int2) * NE;      // (src, w) pairs
  short* w1t     = (short*)p;               p += sizeof(short) * DIN * DIN;
  short* w2t     = (short*)p;               p += sizeof(short) * DIN * DOUT;
  short* h0      = (short*)p;               p += sizeof(short) * (size_t)NN * DIN;  // bf16
  short* acc1    = (short*)p;               // [NN, DIN] bf16
  int*   next    = cnt;                     // cnt dead after scan_local
  short* h2      = h0;                      // h0 dead after spmm1; [NN, DOUT] bf16

  // CSR build + weight prep
  hipMemsetAsync(cnt, 0, sizeof(int) * NN, stream);
  hist_prep_kernel<<<HIST_B + PREP_B, 256, 0, stream>>>(ei, cnt, W1, w1t, W2, w2t);
  scan_local_kernel<<<NBLK, 256, 0, stream>>>(cnt, row_ptr, blk_sum);
  scan_blk_kernel<<<1, 512, 0, stream>>>(blk_sum, blk_off);
  scan_add_kernel<<<NBLK, 256, 0, stream>>>(row_ptr, blk_off, next);
  scatter_kernel<<<HIST_B, 256, 0, stream>>>(ei, ew, next, ep);

  // layer 1
  gemm1_mfma_kernel<<<(NN + G1_BM - 1) / G1_BM, 256, 0, stream>>>(x, w1t, h0);
  spmm_gather_kernel<DIN, 16, false, true>
      <<<(NN * 16 + 255) / 256, 256, 0, stream>>>(row_ptr, ep, h0, nullptr, acc1);

  // layer 2
  gemm2_mfma_kernel<<<(NN + G1_BM - 1) / G1_BM, 256, 0, stream>>>(acc1, b1, w2t, h2);
  spmm_gather_kernel<DOUT, 8, true, false>
      <<<(NN * 8 + 255) / 256, 256, 0, stream>>>(row_ptr, ep, h2, b2, out);
}

// Round 10
// 235.315 us; speedup vs baseline: 1.6971x; 1.1119x over previous
//
#include <hip/hip_runtime.h>

#define NN 100000
#define NE 600000
#define DIN 128
#define DOUT 64
#define SCAN_B 512
#define NBLK ((NN + SCAN_B - 1) / SCAN_B)  // 196
#define HIST_B ((NE + 255) / 256)          // 2344
#define PREP_N (DIN * DIN + DIN * DOUT)    // 24576
#define PREP_B ((PREP_N + 255) / 256)      // 96

typedef __attribute__((ext_vector_type(8))) short bf16x8;
typedef __attribute__((ext_vector_type(4))) short s16x4;
typedef __attribute__((ext_vector_type(4))) float f32x4;
typedef __attribute__((ext_vector_type(2))) float f32x2;

__device__ inline short f2bf(float f) {  // RTN-even fp32 -> bf16 bits
  union { float f; unsigned u; } v; v.f = f;
  unsigned r = (v.u + 0x7FFF + ((v.u >> 16) & 1)) >> 16;
  return (short)r;
}
__device__ inline float bf2f(unsigned short u) {
  union { unsigned u; float f; } v; v.u = ((unsigned)u) << 16;
  return v.f;
}
__device__ inline unsigned char f2fp8(float f) {  // HW e4m3 (OCP on gfx950)
  unsigned pk = __builtin_amdgcn_cvt_pk_fp8_f32(f, f, 0, false);
  return (unsigned char)(pk & 0xff);
}
// 16 fp8 bytes -> 16 f32 FMAs into acc[]
__device__ inline void fma_fp8x16(uint4 q, float w, float* acc) {
  f32x2 f;
  f = __builtin_amdgcn_cvt_pk_f32_fp8(q.x, false); acc[0] += w * f[0];  acc[1] += w * f[1];
  f = __builtin_amdgcn_cvt_pk_f32_fp8(q.x, true);  acc[2] += w * f[0];  acc[3] += w * f[1];
  f = __builtin_amdgcn_cvt_pk_f32_fp8(q.y, false); acc[4] += w * f[0];  acc[5] += w * f[1];
  f = __builtin_amdgcn_cvt_pk_f32_fp8(q.y, true);  acc[6] += w * f[0];  acc[7] += w * f[1];
  f = __builtin_amdgcn_cvt_pk_f32_fp8(q.z, false); acc[8] += w * f[0];  acc[9] += w * f[1];
  f = __builtin_amdgcn_cvt_pk_f32_fp8(q.z, true);  acc[10] += w * f[0]; acc[11] += w * f[1];
  f = __builtin_amdgcn_cvt_pk_f32_fp8(q.w, false); acc[12] += w * f[0]; acc[13] += w * f[1];
  f = __builtin_amdgcn_cvt_pk_f32_fp8(q.w, true);  acc[14] += w * f[0]; acc[15] += w * f[1];
}

// ------- hist (+ rank capture + fused W1^T / W2^T bf16 prep) ----------------
__global__ __launch_bounds__(256) void hist_prep_kernel(const int* __restrict__ ei,
                                                        int* __restrict__ cnt,
                                                        int* __restrict__ rank,
                                                        const float* __restrict__ W1,
                                                        short* __restrict__ w1t,
                                                        const float* __restrict__ W2,
                                                        short* __restrict__ w2t) {
  const int b = blockIdx.x, t = threadIdx.x;
  if (b < HIST_B) {
    int e = b * 256 + t;
    if (e < NE) rank[e] = atomicAdd(&cnt[ei[NE + e]], 1);  // rank = old count
  } else {
    int i = (b - HIST_B) * 256 + t;
    if (i < DIN * DIN) {
      int n = i >> 7, k = i & 127;
      w1t[i] = f2bf(W1[k * DIN + n]);            // w1t[n][k]
    } else if (i < PREP_N) {
      int i2 = i - DIN * DIN;
      int n = i2 >> 7, k = i2 & 127;
      w2t[i2] = f2bf(W2[k * DOUT + n]);          // w2t[n][k]
    }
  }
}

__global__ __launch_bounds__(512) void scan_local_kernel(const int* __restrict__ cnt,
                                                         int* __restrict__ row_ptr,
                                                         int* __restrict__ blk_sum) {
  __shared__ int s[512];
  const int b = blockIdx.x, t = threadIdx.x;
  const int i = b * 512 + t;
  int v = (i < NN) ? cnt[i] : 0;
  s[t] = v;
  __syncthreads();
  for (int off = 1; off < 512; off <<= 1) {
    int u = (t >= off) ? s[t - off] : 0;
    __syncthreads();
    s[t] += u;
    __syncthreads();
  }
  if (i < NN) row_ptr[i] = s[t] - v;  // block-local exclusive
  if (t == 511) blk_sum[b] = s[511];
}

// each block redundantly scans the 196 block sums in LDS, adds its offset
__global__ __launch_bounds__(512) void scan_add_kernel(int* __restrict__ row_ptr,
                                                       const int* __restrict__ blk_sum) {
  __shared__ int s[512];
  const int b = blockIdx.x, t = threadIdx.x;
  s[t] = (t < NBLK) ? blk_sum[t] : 0;
  __syncthreads();
  for (int off = 1; off < 512; off <<= 1) {
    int u = (t >= off) ? s[t - off] : 0;
    __syncthreads();
    s[t] += u;
    __syncthreads();
  }
  int off = (b > 0) ? s[b - 1] : 0;  // inclusive scan -> exclusive block offset
  const int i = b * 512 + t;
  if (i < NN) row_ptr[i] += off;
  if (b == 0 && t == 0) row_ptr[NN] = NE;
}

// atomic-free scatter: pos = row_ptr[dst] + rank[e]
__global__ __launch_bounds__(256) void scatter_kernel(const int* __restrict__ ei,
                                                      const float* __restrict__ ew,
                                                      const int* __restrict__ row_ptr,
                                                      const int* __restrict__ rank,
                                                      int2* __restrict__ ep) {
  int e = blockIdx.x * 256 + threadIdx.x;
  if (e >= NE) return;
  int src = ei[e];
  int dst = ei[NE + e];
  int pos = row_ptr[dst] + rank[e];
  ep[pos] = make_int2(src, __float_as_int(ew[e]));
}

// ---------------- GEMM1 via MFMA bf16: h0(fp8 e4m3) = x @ W1 ----------------
#define G1_BM 128
#define XS_PITCH 136
__global__ __launch_bounds__(256) void gemm1_mfma_kernel(const float* __restrict__ x,
                                                         const short* __restrict__ w1t,
                                                         unsigned char* __restrict__ h0) {
  __shared__ short xs[G1_BM][XS_PITCH];
  const int t = threadIdx.x;
  const int row0 = blockIdx.x * G1_BM;
#pragma unroll
  for (int i = 0; i < 16; ++i) {
    int f = t + i * 256;
    int r = f >> 5, c4 = f & 31;
    int gr = row0 + r;
    float4 v = (gr < NN) ? *(const float4*)&x[(size_t)gr * DIN + c4 * 4]
                         : make_float4(0.f, 0.f, 0.f, 0.f);
    s16x4 s;
    s.x = f2bf(v.x); s.y = f2bf(v.y); s.z = f2bf(v.z); s.w = f2bf(v.w);
    *(s16x4*)&xs[r][c4 * 4] = s;
  }
  __syncthreads();

  const int wave = t >> 6, lane = t & 63;
  const int nlane = lane & 15, quad = lane >> 4;
  const int mbase = wave * 32;
  f32x4 acc[2][8];
#pragma unroll
  for (int mt = 0; mt < 2; ++mt)
#pragma unroll
    for (int nt = 0; nt < 8; ++nt) acc[mt][nt] = (f32x4){0.f, 0.f, 0.f, 0.f};

#pragma unroll
  for (int ks = 0; ks < 4; ++ks) {
    const int koff = ks * 32 + quad * 8;
    bf16x8 a0 = *(const bf16x8*)&xs[mbase + nlane][koff];
    bf16x8 a1 = *(const bf16x8*)&xs[mbase + 16 + nlane][koff];
#pragma unroll
    for (int nt = 0; nt < 8; ++nt) {
      bf16x8 b = *(const bf16x8*)&w1t[(size_t)(nt * 16 + nlane) * DIN + koff];
      acc[0][nt] = __builtin_amdgcn_mfma_f32_16x16x32_bf16(a0, b, acc[0][nt], 0, 0, 0);
      acc[1][nt] = __builtin_amdgcn_mfma_f32_16x16x32_bf16(a1, b, acc[1][nt], 0, 0, 0);
    }
  }

#pragma unroll
  for (int mt = 0; mt < 2; ++mt)
#pragma unroll
    for (int nt = 0; nt < 8; ++nt)
#pragma unroll
      for (int rg = 0; rg < 4; ++rg) {
        int gr = row0 + mbase + mt * 16 + quad * 4 + rg;
        if (gr < NN) h0[(size_t)gr * DIN + nt * 16 + nlane] = f2fp8(acc[mt][nt][rg]);
      }
}

// -------- GEMM2 via MFMA bf16: h2(bf16) = relu(acc1(bf16) + b1) @ W2 --------
__global__ __launch_bounds__(256) void gemm2_mfma_kernel(const short* __restrict__ acc1,
                                                         const float* __restrict__ b1,
                                                         const short* __restrict__ w2t,
                                                         short* __restrict__ h2) {
  __shared__ short xs[G1_BM][XS_PITCH];
  const int t = threadIdx.x;
  const int row0 = blockIdx.x * G1_BM;
#pragma unroll
  for (int i = 0; i < 8; ++i) {
    int f = t + i * 256;
    int r = f >> 4, c8 = f & 15;
    int gr = row0 + r;
    bf16x8 v = (gr < NN) ? *(const bf16x8*)&acc1[(size_t)gr * DIN + c8 * 8]
                         : (bf16x8){0, 0, 0, 0, 0, 0, 0, 0};
    bf16x8 s;
#pragma unroll
    for (int j = 0; j < 8; ++j) {
      float fv = bf2f((unsigned short)v[j]) + b1[c8 * 8 + j];
      s[j] = f2bf(fmaxf(fv, 0.f));
    }
    *(bf16x8*)&xs[r][c8 * 8] = s;
  }
  __syncthreads();

  const int wave = t >> 6, lane = t & 63;
  const int nlane = lane & 15, quad = lane >> 4;
  const int mbase = wave * 32;
  f32x4 acc[2][4];
#pragma unroll
  for (int mt = 0; mt < 2; ++mt)
#pragma unroll
    for (int nt = 0; nt < 4; ++nt) acc[mt][nt] = (f32x4){0.f, 0.f, 0.f, 0.f};

#pragma unroll
  for (int ks = 0; ks < 4; ++ks) {
    const int koff = ks * 32 + quad * 8;
    bf16x8 a0 = *(const bf16x8*)&xs[mbase + nlane][koff];
    bf16x8 a1 = *(const bf16x8*)&xs[mbase + 16 + nlane][koff];
#pragma unroll
    for (int nt = 0; nt < 4; ++nt) {
      bf16x8 b = *(const bf16x8*)&w2t[(size_t)(nt * 16 + nlane) * DIN + koff];
      acc[0][nt] = __builtin_amdgcn_mfma_f32_16x16x32_bf16(a0, b, acc[0][nt], 0, 0, 0);
      acc[1][nt] = __builtin_amdgcn_mfma_f32_16x16x32_bf16(a1, b, acc[1][nt], 0, 0, 0);
    }
  }

#pragma unroll
  for (int mt = 0; mt < 2; ++mt)
#pragma unroll
    for (int nt = 0; nt < 4; ++nt)
#pragma unroll
      for (int rg = 0; rg < 4; ++rg) {
        int gr = row0 + mbase + mt * 16 + quad * 4 + rg;
        if (gr < NN) h2[(size_t)gr * DOUT + nt * 16 + nlane] = f2bf(acc[mt][nt][rg]);
      }
}

// ------- spmm1: acc1(bf16) = A @ h0(fp8), LPE=8, lane owns 16 elems ---------
__global__ __launch_bounds__(256) void spmm1_fp8_kernel(const int* __restrict__ rp,
                                                        const int2* __restrict__ ep,
                                                        const unsigned char* __restrict__ h,
                                                        short* __restrict__ acc1) {
  const int row = blockIdx.x * 32 + (threadIdx.x >> 3);
  const int lane = threadIdx.x & 7;  // owns bytes [lane*16, lane*16+16)
  if (row >= NN) return;
  const int b = rp[row], e = rp[row + 1];
  float acc[16];
#pragma unroll
  for (int j = 0; j < 16; ++j) acc[j] = 0.f;
  int i = b;
  for (; i + 4 <= e; i += 4) {
    int2 p0 = ep[i], p1 = ep[i + 1], p2 = ep[i + 2], p3 = ep[i + 3];
    uint4 q0 = *(const uint4*)&h[(size_t)p0.x * DIN + lane * 16];
    uint4 q1 = *(const uint4*)&h[(size_t)p1.x * DIN + lane * 16];
    uint4 q2 = *(const uint4*)&h[(size_t)p2.x * DIN + lane * 16];
    uint4 q3 = *(const uint4*)&h[(size_t)p3.x * DIN + lane * 16];
    fma_fp8x16(q0, __int_as_float(p0.y), acc);
    fma_fp8x16(q1, __int_as_float(p1.y), acc);
    fma_fp8x16(q2, __int_as_float(p2.y), acc);
    fma_fp8x16(q3, __int_as_float(p3.y), acc);
  }
  if (i + 2 <= e) {
    int2 p0 = ep[i], p1 = ep[i + 1];
    uint4 q0 = *(const uint4*)&h[(size_t)p0.x * DIN + lane * 16];
    uint4 q1 = *(const uint4*)&h[(size_t)p1.x * DIN + lane * 16];
    fma_fp8x16(q0, __int_as_float(p0.y), acc);
    fma_fp8x16(q1, __int_as_float(p1.y), acc);
    i += 2;
  }
  if (i < e) {
    int2 p0 = ep[i];
    uint4 q0 = *(const uint4*)&h[(size_t)p0.x * DIN + lane * 16];
    fma_fp8x16(q0, __int_as_float(p0.y), acc);
  }
  bf16x8 o0, o1;
#pragma unroll
  for (int j = 0; j < 8; ++j) { o0[j] = f2bf(acc[j]); o1[j] = f2bf(acc[8 + j]); }
  *(bf16x8*)&acc1[(size_t)row * DIN + lane * 16] = o0;
  *(bf16x8*)&acc1[(size_t)row * DIN + lane * 16 + 8] = o1;
}

// ------- spmm2: out(fp32) = A @ h2(bf16) + b2, LPE=8, lane owns 8 elems -----
__global__ __launch_bounds__(256) void spmm2_kernel(const int* __restrict__ rp,
                                                    const int2* __restrict__ ep,
                                                    const short* __restrict__ h,
                                                    const float* __restrict__ bias,
                                                    float* __restrict__ out) {
  const int row = blockIdx.x * 32 + (threadIdx.x >> 3);
  const int lane = threadIdx.x & 7;  // owns elems [lane*8, lane*8+8)
  if (row >= NN) return;
  const int b = rp[row], e = rp[row + 1];
  float acc[8];
#pragma unroll
  for (int j = 0; j < 8; ++j) acc[j] = 0.f;
  int i = b;
  for (; i + 4 <= e; i += 4) {
    int2 p0 = ep[i], p1 = ep[i + 1], p2 = ep[i + 2], p3 = ep[i + 3];
    bf16x8 v0 = *(const bf16x8*)&h[(size_t)p0.x * DOUT + lane * 8];
    bf16x8 v1 = *(const bf16x8*)&h[(size_t)p1.x * DOUT + lane * 8];
    bf16x8 v2 = *(const bf16x8*)&h[(size_t)p2.x * DOUT + lane * 8];
    bf16x8 v3 = *(const bf16x8*)&h[(size_t)p3.x * DOUT + lane * 8];
    float w0 = __int_as_float(p0.y), w1 = __int_as_float(p1.y);
    float w2 = __int_as_float(p2.y), w3 = __int_as_float(p3.y);
#pragma unroll
    for (int j = 0; j < 8; ++j)
      acc[j] += w0 * bf2f((unsigned short)v0[j]) + w1 * bf2f((unsigned short)v1[j]) +
                w2 * bf2f((unsigned short)v2[j]) + w3 * bf2f((unsigned short)v3[j]);
  }
  if (i + 2 <= e) {
    int2 p0 = ep[i], p1 = ep[i + 1];
    bf16x8 v0 = *(const bf16x8*)&h[(size_t)p0.x * DOUT + lane * 8];
    bf16x8 v1 = *(const bf16x8*)&h[(size_t)p1.x * DOUT + lane * 8];
    float w0 = __int_as_float(p0.y), w1 = __int_as_float(p1.y);
#pragma unroll
    for (int j = 0; j < 8; ++j)
      acc[j] += w0 * bf2f((unsigned short)v0[j]) + w1 * bf2f((unsigned short)v1[j]);
    i += 2;
  }
  if (i < e) {
    int2 p0 = ep[i];
    bf16x8 v0 = *(const bf16x8*)&h[(size_t)p0.x * DOUT + lane * 8];
    float w0 = __int_as_float(p0.y);
#pragma unroll
    for (int j = 0; j < 8; ++j) acc[j] += w0 * bf2f((unsigned short)v0[j]);
  }
#pragma unroll
  for (int j = 0; j < 8; ++j) acc[j] += bias[lane * 8 + j];
  *(float4*)&out[(size_t)row * DOUT + lane * 8] = make_float4(acc[0], acc[1], acc[2], acc[3]);
  *(float4*)&out[(size_t)row * DOUT + lane * 8 + 4] = make_float4(acc[4], acc[5], acc[6], acc[7]);
}

extern "C" void kernel_launch(void* const* d_in, const int* in_sizes, int n_in,
                              void* d_out, int out_size, void* d_ws, size_t ws_size,
                              hipStream_t stream) {
  const float* x  = (const float*)d_in[0];
  const int*   ei = (const int*)d_in[1];
  const float* ew = (const float*)d_in[2];
  const float* W1 = (const float*)d_in[3];
  const float* b1 = (const float*)d_in[4];
  const float* W2 = (const float*)d_in[5];
  const float* b2 = (const float*)d_in[6];
  float* out = (float*)d_out;

  // workspace layout — ~46.5 MB (82.4 MB proven safe)
  char* p = (char*)d_ws;
  int*   cnt     = (int*)p;                 p += sizeof(int) * NN;
  int*   row_ptr = (int*)p;                 p += sizeof(int) * (NN + 4);
  int*   blk_sum = (int*)p;                 p += sizeof(int) * (NBLK + 4);
  int*   rank    = (int*)p;                 p += sizeof(int) * NE;
  int2*  ep      = (int2*)p;                p += sizeof(int2) * NE;      // (src, w)
  short* w1t     = (short*)p;               p += sizeof(short) * DIN * DIN;
  short* w2t     = (short*)p;               p += sizeof(short) * DIN * DOUT;
  unsigned char* h0 = (unsigned char*)p;    p += (size_t)NN * DIN;      // fp8 e4m3
  short* acc1    = (short*)p;               // [NN, DIN] bf16
  short* h2      = (short*)h0;              // h0 dead after spmm1; [NN, DOUT] bf16 (12.8 MB, fits)

  // CSR build + weight prep
  hipMemsetAsync(cnt, 0, sizeof(int) * NN, stream);
  hist_prep_kernel<<<HIST_B + PREP_B, 256, 0, stream>>>(ei, cnt, rank, W1, w1t, W2, w2t);
  scan_local_kernel<<<NBLK, 512, 0, stream>>>(cnt, row_ptr, blk_sum);
  scan_add_kernel<<<NBLK, 512, 0, stream>>>(row_ptr, blk_sum);
  scatter_kernel<<<HIST_B, 256, 0, stream>>>(ei, ew, row_ptr, rank, ep);

  // layer 1
  gemm1_mfma_kernel<<<(NN + G1_BM - 1) / G1_BM, 256, 0, stream>>>(x, w1t, h0);
  spmm1_fp8_kernel<<<(NN + 31) / 32, 256, 0, stream>>>(row_ptr, ep, h0, acc1);

  // layer 2
  gemm2_mfma_kernel<<<(NN + G1_BM - 1) / G1_BM, 256, 0, stream>>>(acc1, b1, w2t, h2);
  spmm2_kernel<<<(NN + 31) / 32, 256, 0, stream>>>(row_ptr, ep, h2, b2, out);
}